// Round 1
// baseline (217.782 us; speedup 1.0000x reference)
//
#include <hip/hip_runtime.h>

#define HID 2048
#define NEXP 64
#define NTOK 16384
#define TM 32            // tokens per block (one 32-row MFMA tile)
#define NTHREADS 512     // 8 waves
#define NCHUNK 32        // HID / 64
#define KPH 8            // K-phases = waves per block
#define CPW 4            // chunks per wave (NCHUNK / KPH)
#define TPW 4            // tokens per wave in epilogue (TM / KPH)
#define WS_W_OFF 1024    // W planes start here in d_ws (accum in [0,512))
#define CHUNK_B 24576    // 4 ksteps * 3 planes * 2 halves * 1024 B

// out layout (f32): weights [0,32768) | indices [32768,65536) | aux 65536 | counts [65537,65601)
#define OUT_IDX_OFF (2 * NTOK)
#define OUT_AUX_OFF (4 * NTOK)
#define OUT_CNT_OFF (4 * NTOK + 1)

typedef __attribute__((ext_vector_type(8))) short bhalf8;    // 8 bf16 = 4 VGPRs (A/B frag)
typedef __attribute__((ext_vector_type(16))) float f32x16;   // 32x32 C/D frag

// Exact 3-way RNE bf16 split (for W, precomputed): v == h1+h2+h3 exactly.
__device__ __forceinline__ void split3(float v, unsigned short& h1, unsigned short& h2, unsigned short& h3) {
    unsigned int u = __float_as_uint(v);
    unsigned int r1 = (u + 0x7FFFu + ((u >> 16) & 1u)) & 0xFFFF0000u;
    float f1 = __uint_as_float(r1);
    float d1 = v - f1;
    unsigned int u2 = __float_as_uint(d1);
    unsigned int r2 = (u2 + 0x7FFFu + ((u2 >> 16) & 1u)) & 0xFFFF0000u;
    float f2 = __uint_as_float(r2);
    float d2 = d1 - f2;
    h1 = (unsigned short)(r1 >> 16);
    h2 = (unsigned short)(r2 >> 16);
    h3 = (unsigned short)(__float_as_uint(d2) >> 16);
}

// Truncating 3-plane split of 8 fp32 -> three bf16x8 A-frags, in registers.
__device__ __forceinline__ void xsplit(float4 va, float4 vb, bhalf8& o1, bhalf8& o2, bhalf8& o3) {
    float f[8] = {va.x, va.y, va.z, va.w, vb.x, vb.y, vb.z, vb.w};
    union U { bhalf8 v; unsigned int u[4]; } u1, u2, u3;
#pragma unroll
    for (int t = 0; t < 4; t++) {
        float a = f[2 * t], b = f[2 * t + 1];
        unsigned int ua = __float_as_uint(a), ub = __float_as_uint(b);
        float da = a - __uint_as_float(ua & 0xFFFF0000u);
        float db = b - __uint_as_float(ub & 0xFFFF0000u);
        unsigned int uda = __float_as_uint(da), udb = __float_as_uint(db);
        float da2 = da - __uint_as_float(uda & 0xFFFF0000u);
        float db2 = db - __uint_as_float(udb & 0xFFFF0000u);
        u1.u[t] = (ua >> 16) | (ub & 0xFFFF0000u);
        u2.u[t] = (uda >> 16) | (udb & 0xFFFF0000u);
        u3.u[t] = (__float_as_uint(da2) >> 16) | (__float_as_uint(db2) & 0xFFFF0000u);
    }
    o1 = u1.v; o2 = u2.v; o3 = u3.v;
}

// ---- pre-kernel: split W into 3 bf16 planes in coalesced B-fragment layout ----
// 256 blocks x 64 threads: spread across all CUs (was 64 blocks -> 64 CUs).
__global__ __launch_bounds__(64) void wsplit_kernel(const float* __restrict__ W,
                                                    char* __restrict__ wq,
                                                    float* __restrict__ wsf) {
    if (blockIdx.x < 2) wsf[blockIdx.x * 64 + threadIdx.x] = 0.f;   // zero accum[0,128)
    int idx8 = (blockIdx.x * 64 + threadIdx.x) * 8;   // 16384 threads x 8 elems
    int e = idx8 >> 11;
    int k0 = idx8 & 2047;                // octet-aligned k
    int c = k0 >> 6, ks = (k0 >> 4) & 3, half = (k0 >> 3) & 1;
    int g = e >> 5, l = (e & 31) + 32 * half;
    const float4* wp = (const float4*)(W + (size_t)e * HID + k0);
    float4 v0 = wp[0], v1 = wp[1];
    float f[8] = {v0.x, v0.y, v0.z, v0.w, v1.x, v1.y, v1.z, v1.w};
    unsigned int p1[4], p2[4], p3[4];
#pragma unroll
    for (int t = 0; t < 4; t++) {
        unsigned short a1, a2, a3, b1, b2, b3;
        split3(f[2 * t], a1, a2, a3);
        split3(f[2 * t + 1], b1, b2, b3);
        p1[t] = (unsigned int)a1 | ((unsigned int)b1 << 16);
        p2[t] = (unsigned int)a2 | ((unsigned int)b2 << 16);
        p3[t] = (unsigned int)a3 | ((unsigned int)b3 << 16);
    }
    char* base = wq + (size_t)(((c * 4 + ks) * 3 + 0) * 2 + g) * 1024 + l * 16;
    *(uint4*)(base)        = make_uint4(p1[0], p1[1], p1[2], p1[3]);   // plane 1
    *(uint4*)(base + 2048) = make_uint4(p2[0], p2[1], p2[2], p2[3]);   // plane 2
    *(uint4*)(base + 4096) = make_uint4(p3[0], p3[1], p3[2], p3[3]);   // plane 3
}

__global__ __launch_bounds__(NTHREADS, 4) void router_main(
    const float* __restrict__ x, const char* __restrict__ wq,
    float* __restrict__ out, float* __restrict__ ws_accum)
{
    __shared__ float slab[KPH * TM * 68];   // 69632 B: per-kphase partial logits
    __shared__ float scount[NEXP];
    __shared__ float sprob[NEXP];

    const int tid = threadIdx.x;
    const int w = tid >> 6;        // kphase / wave id
    const int lane = tid & 63;
    const int r = lane & 31;       // A row / token within tile; B expert within group
    const int h = lane >> 5;       // k-octet half
    const int n0 = blockIdx.x * TM;

    const float* xrow = x + (size_t)(n0 + r) * HID + h * 8;

    f32x16 acc0, acc1;
#pragma unroll
    for (int i = 0; i < 16; i++) { acc0[i] = 0.f; acc1[i] = 0.f; }

    // ---- free-running K-loop: no LDS, no barriers ----
#pragma unroll 1
    for (int i = 0; i < CPW; ++i) {
        const int c = w * CPW + i;
        const float* xc = xrow + c * 64;
        float4 pxa[4], pxb[4];
#pragma unroll
        for (int ks = 0; ks < 4; ks++) {
            pxa[ks] = *(const float4*)(xc + ks * 16);
            pxb[ks] = *(const float4*)(xc + ks * 16 + 4);
        }
        const char* wc = wq + (size_t)c * CHUNK_B + lane * 16;
#pragma unroll
        for (int ks = 0; ks < 4; ks++) {
            bhalf8 A1, A2, A3;
            xsplit(pxa[ks], pxb[ks], A1, A2, A3);
            const char* wk = wc + ks * 6144;
            // all 6 B-frags of this kstep up front -> scheduler can batch the loads
            bhalf8 B1 = *(const bhalf8*)(wk);
            bhalf8 B2 = *(const bhalf8*)(wk + 2048);
            bhalf8 B3 = *(const bhalf8*)(wk + 4096);
            bhalf8 C1 = *(const bhalf8*)(wk + 1024);
            bhalf8 C2 = *(const bhalf8*)(wk + 2048 + 1024);
            bhalf8 C3 = *(const bhalf8*)(wk + 4096 + 1024);
            acc0 = __builtin_amdgcn_mfma_f32_32x32x16_bf16(A1, B1, acc0, 0, 0, 0);
            acc0 = __builtin_amdgcn_mfma_f32_32x32x16_bf16(A1, B2, acc0, 0, 0, 0);
            acc0 = __builtin_amdgcn_mfma_f32_32x32x16_bf16(A2, B1, acc0, 0, 0, 0);
            acc0 = __builtin_amdgcn_mfma_f32_32x32x16_bf16(A1, B3, acc0, 0, 0, 0);
            acc0 = __builtin_amdgcn_mfma_f32_32x32x16_bf16(A2, B2, acc0, 0, 0, 0);
            acc0 = __builtin_amdgcn_mfma_f32_32x32x16_bf16(A3, B1, acc0, 0, 0, 0);
            acc1 = __builtin_amdgcn_mfma_f32_32x32x16_bf16(A1, C1, acc1, 0, 0, 0);
            acc1 = __builtin_amdgcn_mfma_f32_32x32x16_bf16(A1, C2, acc1, 0, 0, 0);
            acc1 = __builtin_amdgcn_mfma_f32_32x32x16_bf16(A2, C1, acc1, 0, 0, 0);
            acc1 = __builtin_amdgcn_mfma_f32_32x32x16_bf16(A1, C3, acc1, 0, 0, 0);
            acc1 = __builtin_amdgcn_mfma_f32_32x32x16_bf16(A2, C2, acc1, 0, 0, 0);
            acc1 = __builtin_amdgcn_mfma_f32_32x32x16_bf16(A3, C1, acc1, 0, 0, 0);
        }
    }

    // ---- combine: each wave stores its partial tile to its slab ----
    // C/D 32x32 layout: col = lane&31, row = (reg&3) + 8*(reg>>2) + 4*(lane>>5)  [m74/m101]
#pragma unroll
    for (int reg = 0; reg < 16; reg++) {
        int row = (reg & 3) + 8 * (reg >> 2) + 4 * h;
        slab[(w * TM + row) * 68 + r]      = acc0[reg];
        slab[(w * TM + row) * 68 + 32 + r] = acc1[reg];
    }
    if (tid < NEXP) { scount[tid] = 0.f; sprob[tid] = 0.f; }
    __syncthreads();

    // reduce KPH kphase slabs into slab[0] (each (t,e) owned by exactly one thread)
    float* logits = slab;
#pragma unroll
    for (int idx = tid; idx < TM * NEXP; idx += NTHREADS) {
        int t = idx >> 6, e = idx & 63;
        float v = 0.f;
#pragma unroll
        for (int p = 0; p < KPH; p++) v += slab[(p * TM + t) * 68 + e];
        logits[t * 68 + e] = v;
    }
    __syncthreads();

    // ---- wave-parallel epilogue: wave w handles tokens w*TPW .. w*TPW+3 ----
    // lane = expert index; per token: 64-lane top-2 butterfly + wave-sum for Z.
    float pacc = 0.f;   // per-lane (expert=lane) sum over this wave's tokens of softmax prob
#pragma unroll 1
    for (int j = 0; j < TPW; j++) {
        const int t = w * TPW + j;
        const float v = logits[t * 68 + lane];
        float m1 = v, m2 = -3.4e38f;
        int i1 = lane, i2 = 0;
#pragma unroll
        for (int off = 32; off > 0; off >>= 1) {
            float om1 = __shfl_xor(m1, off);
            int   oi1 = __shfl_xor(i1, off);
            float om2 = __shfl_xor(m2, off);
            int   oi2 = __shfl_xor(i2, off);
            if (om1 > m1 || (om1 == m1 && oi1 < i1)) {
                // other's top wins; our old top competes for second
                if (m1 > om2 || (m1 == om2 && i1 < oi2)) { m2 = m1; i2 = i1; }
                else { m2 = om2; i2 = oi2; }
                m1 = om1; i1 = oi1;
            } else {
                if (om1 > m2 || (om1 == m2 && oi1 < i2)) { m2 = om1; i2 = oi1; }
            }
        }
        // all lanes converged on (m1,i1,m2,i2)
        float p = __expf(v - m1);
        float Z = p;
#pragma unroll
        for (int off = 32; off > 0; off >>= 1) Z += __shfl_xor(Z, off);
        float invZ = 1.f / Z;
        pacc += p * invZ;
        if (lane == 0) {
            float p1 = invZ;                       // exp(m1-m1)*invZ
            float p2 = __expf(m2 - m1) * invZ;
            float denom = p1 + p2 + 1e-6f;
            int n = n0 + t;
            out[2 * n + 0] = p1 / denom;
            out[2 * n + 1] = p2 / denom;
            out[OUT_IDX_OFF + 2 * n + 0] = (float)i1;
            out[OUT_IDX_OFF + 2 * n + 1] = (float)i2;
            atomicAdd(&scount[i1], 1.f);
            atomicAdd(&scount[i2], 1.f);
        }
    }
    atomicAdd(&sprob[lane], pacc);   // combine per-expert prob sums across 8 waves
    __syncthreads();

    if (tid < NEXP) {
        atomicAdd(&ws_accum[tid], sprob[tid]);
        atomicAdd(&ws_accum[NEXP + tid], scount[tid]);
    }
}

__global__ void router_finish(const float* __restrict__ ws_accum,
                              float* __restrict__ out)
{
    const int e = threadIdx.x;   // 64 threads = 1 wave
    const float invN = 1.f / (float)NTOK;
    float p = ws_accum[e] * invN;
    float a = ws_accum[NEXP + e] * invN;
    float v = p * p + a * a;
#pragma unroll
    for (int off = 32; off > 0; off >>= 1)
        v += __shfl_down(v, off);
    if (e == 0) out[OUT_AUX_OFF] = v * (float)NEXP;
    out[OUT_CNT_OFF + e] = ws_accum[NEXP + e];
}

extern "C" void kernel_launch(void* const* d_in, const int* in_sizes, int n_in,
                              void* d_out, int out_size, void* d_ws, size_t ws_size,
                              hipStream_t stream)
{
    const float* x = (const float*)d_in[0];   // [4,4096,2048] f32
    const float* W = (const float*)d_in[1];   // [64,2048] f32
    float* out = (float*)d_out;
    float* wsf = (float*)d_ws;
    char* wq = (char*)d_ws + WS_W_OFF;        // W planes: 32 chunks x 24576 B = 768 KB

    wsplit_kernel<<<256, 64, 0, stream>>>(W, wq, wsf);   // also zeros accum region
    router_main<<<NTOK / TM, NTHREADS, 0, stream>>>(x, wq, out, wsf);
    router_finish<<<1, 64, 0, stream>>>(wsf, out);
}